// Round 3
// baseline (442.902 us; speedup 1.0000x reference)
//
#include <hip/hip_runtime.h>
#include <hip/hip_bf16.h>

// ---------------------------------------------------------------------------
// concat(x1,x2) -> LSTM(551->128, T=5) -> MLP 640->531->256->64->2 -> softmax
// R3: FULL FUSION. One kernel does xgemm+recurrence+MLP per 32 samples.
//  - x streamed fp32->bf16 straight into A-fragments (no LDS staging, no
//    barriers in the k-loop; 8 waves share the stream via L1).
//  - Gate accumulators live in AGPRs across x@W_ih and h@W_hh (W_hh in regs).
//  - h_t written to LDS `aflat`, which doubles as the MLP layer-1 input.
//  - xg (168 MB traffic) and hs (42 MB) eliminated entirely.
// Wave w owns gate-tiles {g*8+w} (n = g*128 + w*16 + c16), so i/f/g/o for one
// (m,j) land in the same lane -> c stays in registers.
// ---------------------------------------------------------------------------

typedef short  short8  __attribute__((ext_vector_type(8)));
typedef float  f32x4   __attribute__((ext_vector_type(4)));

#define MFMA(a, b, c) __builtin_amdgcn_mfma_f32_16x16x32_bf16((a), (b), (c), 0, 0, 0)

__device__ __forceinline__ short f2bs(float f) {
    __hip_bfloat16 h = __float2bfloat16(f);   // RNE
    union { __hip_bfloat16 h; short s; } u; u.h = h; return u.s;
}
__device__ __forceinline__ float b2f(short s) {
    union { unsigned u; float f; } v; v.u = ((unsigned)(unsigned short)s) << 16; return v.f;
}
__device__ __forceinline__ float sigf(float x)  { return 1.f / (1.f + __expf(-x)); }
__device__ __forceinline__ float mytanh(float x){ return 2.f / (1.f + __expf(-2.f * x)) - 1.f; }

// ---------------- constants ----------------
#define TT     5
#define F1     300
#define F2     251
#define INF    551
#define G4     512
#define HH     128
#define FLAT   640          // T*H (20 k-tiles)
#define L1N    531
#define L1KP   544          // 17 k-tiles
#define L2N    256

// ws offsets (bytes) — weights only now
#define O_WIH  0u
#define O_WHH  589824u
#define O_W1   720896u
#define O_W2   1458176u
#define O_W3   1736704u
#define O_BG   1769472u
#define O_B1   1771520u
#define WS_NEED 1773824u

// LDS plan (shorts): aflat [32][648] at 0 (20736); a1 [32][584] at 20736.
// After aflat dies (post-L1): a2 [32][264] at 0; a3 [32][72] at 8448.
#define SM_TOTAL 39424
#define AFL_STR  648
#define A1_OFF   20736
#define A1_STR   584
#define A2_OFF   0
#define A2_STR   264
#define A3_OFF   8448
#define A3_STR   72

// ---------------------------------------------------------------------------
// prep: weights fp32 -> bf16, packed in B-fragment tile order
//   tile (tn,tk) at ((tn*tilesPerN... ) <<9) + lane*8 + j,
//   lane = ((k>>3)&3)*16 + (n&15), j = k&7
// ---------------------------------------------------------------------------
__device__ __forceinline__ void pack_b(const float* __restrict__ W, short* __restrict__ dst,
                                       int i, int tpn, int Nsrc, int Ksrc, int ldw)
{
    int tile = i >> 9, rem = i & 511, lane = rem >> 3, jj = rem & 7;
    int tn = tile / tpn, tk = tile - tn * tpn;
    int n = tn * 16 + (lane & 15);
    int k = tk * 32 + (lane >> 4) * 8 + jj;
    float v = (n < Nsrc && k < Ksrc) ? W[n * ldw + k] : 0.f;
    dst[i] = f2bs(v);
}

__global__ void prep_kernel(
    const float* __restrict__ W_ih, const float* __restrict__ W_hh,
    const float* __restrict__ b_ih, const float* __restrict__ b_hh,
    const float* __restrict__ W1,   const float* __restrict__ b1,
    const float* __restrict__ W2,   const float* __restrict__ W3,
    short* __restrict__ Wihp, short* __restrict__ Whhp, float* __restrict__ biasg,
    short* __restrict__ W1p,  float* __restrict__ b1p,  short* __restrict__ W2p,
    short* __restrict__ W3p)
{
    const int N0 = G4 * 576;           // Wihp 294912 (18 k-tiles)
    const int N1 = N0 + G4 * HH;       // Whhp (4 k-tiles)
    const int N2 = N1 + 576 * FLAT;    // W1p  (20 k-tiles, N padded to 576)
    const int N3 = N2 + L2N * L1KP;    // W2p  (17 k-tiles)
    const int N4 = N3 + 64 * L2N;      // W3p  (8 k-tiles)
    const int N5 = N4 + G4;            // biasg
    const int N6 = N5 + 576;           // b1p
    const int stride = gridDim.x * blockDim.x;
    for (int i = blockIdx.x * blockDim.x + threadIdx.x; i < N6; i += stride) {
        if (i < N0)      pack_b(W_ih, Wihp, i,       18, G4,  INF, INF);
        else if (i < N1) pack_b(W_hh, Whhp, i - N0,   4, G4,  HH,  HH);
        else if (i < N2) pack_b(W1,   W1p,  i - N1,  20, L1N, FLAT, FLAT);
        else if (i < N3) pack_b(W2,   W2p,  i - N2,  17, L2N, L1N, L1N);
        else if (i < N4) pack_b(W3,   W3p,  i - N3,   8, 64,  L2N, L2N);
        else if (i < N5) { int j = i - N4; biasg[j] = b_ih[j] + b_hh[j]; }
        else             { int j = i - N5; b1p[j] = (j < L1N) ? b1[j] : 0.f; }
    }
}

// ---------------------------------------------------------------------------
// fused kernel: 512 blocks x 512 thr, 32 samples/block.
// ---------------------------------------------------------------------------
__global__ __launch_bounds__(512, 2) void fused_kernel(
    const float* __restrict__ x1, const float* __restrict__ x2,
    const short* __restrict__ Wihp, const short* __restrict__ Whhp,
    const float* __restrict__ biasg,
    const short* __restrict__ W1p, const float* __restrict__ b1p,
    const short* __restrict__ W2p, const float* __restrict__ b2,
    const short* __restrict__ W3p, const float* __restrict__ b3,
    const float* __restrict__ W4,  const float* __restrict__ b4,
    float* __restrict__ out)
{
    __shared__ __align__(16) short sA[SM_TOTAL];
    const int tid  = threadIdx.x;
    const int w    = tid >> 6;
    const int lane = tid & 63;
    const int quad = lane >> 4;
    const int c16  = lane & 15;
    const int b0   = blockIdx.x * 32;
    const int j    = w * 16 + c16;          // gate-local column 0..127

    // gate biases (i,f,g,o) for this thread's column
    float bg[4];
#pragma unroll
    for (int g = 0; g < 4; ++g) bg[g] = biasg[g * HH + j];

    // W_hh B-frags in registers, reused across all t
    short8 whh[4][4];
#pragma unroll
    for (int g = 0; g < 4; ++g)
#pragma unroll
        for (int ks = 0; ks < 4; ++ks)
            whh[g][ks] = *(const short8*)&Whhp[((((g * 8 + w) * 4) + ks) << 9) + lane * 8];

    float cst[2][4];
#pragma unroll
    for (int mt = 0; mt < 2; ++mt)
#pragma unroll
        for (int r = 0; r < 4; ++r) cst[mt][r] = 0.f;

    // ---------------- recurrence over t ----------------
    for (int t = 0; t < TT; ++t) {
        // per-mt row pointers for this t
        const float* x1r[2];
        const float* x2r[2];
#pragma unroll
        for (int mt = 0; mt < 2; ++mt) {
            int brow = b0 + mt * 16 + c16;
            x1r[mt] = x1 + (brow * TT + t) * F1;
            x2r[mt] = x2 + (brow * TT + t) * F2;
        }

        f32x4 acc[2][4];
#pragma unroll
        for (int mt = 0; mt < 2; ++mt)
#pragma unroll
            for (int g = 0; g < 4; ++g)
                acc[mt][g] = (f32x4){0.f, 0.f, 0.f, 0.f};

        // ---- x @ W_ih^T : k-tiles 0..16 streamed, register double-buffer ----
        float4 cur0[2], cur1[2];
#pragma unroll
        for (int mt = 0; mt < 2; ++mt) {
            int k0 = quad * 8;
            cur0[mt] = (k0     < F1) ? *(const float4*)(x1r[mt] + k0)
                                     : *(const float4*)(x2r[mt] + (k0 - F1));
            cur1[mt] = (k0 + 4 < F1) ? *(const float4*)(x1r[mt] + k0 + 4)
                                     : *(const float4*)(x2r[mt] + (k0 + 4 - F1));
        }
        for (int tk = 0; tk < 17; ++tk) {
            short8 afr[2];
#pragma unroll
            for (int mt = 0; mt < 2; ++mt) {
                afr[mt][0] = f2bs(cur0[mt].x); afr[mt][1] = f2bs(cur0[mt].y);
                afr[mt][2] = f2bs(cur0[mt].z); afr[mt][3] = f2bs(cur0[mt].w);
                afr[mt][4] = f2bs(cur1[mt].x); afr[mt][5] = f2bs(cur1[mt].y);
                afr[mt][6] = f2bs(cur1[mt].z); afr[mt][7] = f2bs(cur1[mt].w);
            }
            if (tk < 16) {
#pragma unroll
                for (int mt = 0; mt < 2; ++mt) {
                    int k0 = (tk + 1) * 32 + quad * 8;
                    cur0[mt] = (k0     < F1) ? *(const float4*)(x1r[mt] + k0)
                                             : *(const float4*)(x2r[mt] + (k0 - F1));
                    cur1[mt] = (k0 + 4 < F1) ? *(const float4*)(x1r[mt] + k0 + 4)
                                             : *(const float4*)(x2r[mt] + (k0 + 4 - F1));
                }
            }
#pragma unroll
            for (int g = 0; g < 4; ++g) {
                short8 bfr = *(const short8*)&Wihp[(((g * 8 + w) * 18 + tk) << 9) + lane * 8];
                acc[0][g] = MFMA(afr[0], bfr, acc[0][g]);
                acc[1][g] = MFMA(afr[1], bfr, acc[1][g]);
            }
        }
        // ---- tail k-tile 17 (k 544..575; valid k<551, rest multiplied by 0-pad B) ----
        {
            short8 afr[2];
#pragma unroll
            for (int mt = 0; mt < 2; ++mt) {
#pragma unroll
                for (int jj = 0; jj < 8; ++jj) {
                    int k = 544 + quad * 8 + jj;
                    afr[mt][jj] = (k < INF) ? f2bs(x2r[mt][k - F1]) : (short)0;
                }
            }
#pragma unroll
            for (int g = 0; g < 4; ++g) {
                short8 bfr = *(const short8*)&Wihp[(((g * 8 + w) * 18 + 17) << 9) + lane * 8];
                acc[0][g] = MFMA(afr[0], bfr, acc[0][g]);
                acc[1][g] = MFMA(afr[1], bfr, acc[1][g]);
            }
        }

        // ---- + h_{t-1} @ W_hh^T from LDS ----
        if (t > 0) {
#pragma unroll
            for (int ks = 0; ks < 4; ++ks) {
                short8 ha[2];
#pragma unroll
                for (int mt = 0; mt < 2; ++mt)
                    ha[mt] = *(const short8*)
                        &sA[(mt * 16 + c16) * AFL_STR + (t - 1) * HH + ks * 32 + quad * 8];
#pragma unroll
                for (int g = 0; g < 4; ++g) {
                    acc[0][g] = MFMA(ha[0], whh[g][ks], acc[0][g]);
                    acc[1][g] = MFMA(ha[1], whh[g][ks], acc[1][g]);
                }
            }
        }

        // ---- gates -> c,h ; h into aflat ----
#pragma unroll
        for (int mt = 0; mt < 2; ++mt) {
#pragma unroll
            for (int r = 0; r < 4; ++r) {
                int m = mt * 16 + quad * 4 + r;
                float gi = acc[mt][0][r] + bg[0];
                float gf = acc[mt][1][r] + bg[1];
                float gg = acc[mt][2][r] + bg[2];
                float go = acc[mt][3][r] + bg[3];
                float cn = sigf(gf) * cst[mt][r] + sigf(gi) * mytanh(gg);
                cst[mt][r] = cn;
                sA[m * AFL_STR + t * HH + j] = f2bs(sigf(go) * mytanh(cn));
            }
        }
        __syncthreads();
    }

    // ---------------- MLP ----------------
    // L1: [32x640] @ W1^T -> 576 cols. 36 n-tiles: wave w gets tn = w+8i.
    {
        const int ntc = (w < 4) ? 5 : 4;
        f32x4 acc1[2][5];
#pragma unroll
        for (int mt = 0; mt < 2; ++mt)
#pragma unroll
            for (int i = 0; i < 5; ++i)
                acc1[mt][i] = (f32x4){0.f, 0.f, 0.f, 0.f};
        for (int ks = 0; ks < 20; ++ks) {
            short8 a[2];
#pragma unroll
            for (int mt = 0; mt < 2; ++mt)
                a[mt] = *(const short8*)&sA[(mt * 16 + c16) * AFL_STR + ks * 32 + quad * 8];
#pragma unroll
            for (int i = 0; i < 5; ++i) {
                if (i < ntc) {
                    int tn = w + 8 * i;
                    short8 b = *(const short8*)&W1p[((tn * 20 + ks) << 9) + lane * 8];
                    acc1[0][i] = MFMA(a[0], b, acc1[0][i]);
                    acc1[1][i] = MFMA(a[1], b, acc1[1][i]);
                }
            }
        }
        __syncthreads();   // aflat reads done before a1 writes? (a1 disjoint; sync for t=4 writes already done) -- keep order: writes below
#pragma unroll
        for (int i = 0; i < 5; ++i) {
            if (i < ntc) {
                int tn = w + 8 * i;
                int n  = tn * 16 + c16;
                float bv = b1p[n];
#pragma unroll
                for (int mt = 0; mt < 2; ++mt)
#pragma unroll
                    for (int r = 0; r < 4; ++r) {
                        int m = mt * 16 + quad * 4 + r;
                        float v = acc1[mt][i][r] + bv;
                        sA[A1_OFF + m * A1_STR + n] = f2bs(v > 0.f ? v : 0.f);
                    }
            }
        }
    }
    __syncthreads();

    // L2: K=544, N=256. 16 n-tiles: wave w gets tn = 2w, 2w+1. a2 overwrites aflat.
    {
        f32x4 acc2[2][2];
#pragma unroll
        for (int mt = 0; mt < 2; ++mt)
#pragma unroll
            for (int i = 0; i < 2; ++i)
                acc2[mt][i] = (f32x4){0.f, 0.f, 0.f, 0.f};
        for (int ks = 0; ks < 17; ++ks) {
            short8 a[2];
#pragma unroll
            for (int mt = 0; mt < 2; ++mt)
                a[mt] = *(const short8*)&sA[A1_OFF + (mt * 16 + c16) * A1_STR + ks * 32 + quad * 8];
#pragma unroll
            for (int i = 0; i < 2; ++i) {
                int tn = w * 2 + i;
                short8 b = *(const short8*)&W2p[((tn * 17 + ks) << 9) + lane * 8];
                acc2[0][i] = MFMA(a[0], b, acc2[0][i]);
                acc2[1][i] = MFMA(a[1], b, acc2[1][i]);
            }
        }
#pragma unroll
        for (int i = 0; i < 2; ++i) {
            int n = (w * 2 + i) * 16 + c16;
            float bv = b2[n];
#pragma unroll
            for (int mt = 0; mt < 2; ++mt)
#pragma unroll
                for (int r = 0; r < 4; ++r) {
                    int m = mt * 16 + quad * 4 + r;
                    float v = acc2[mt][i][r] + bv;
                    sA[A2_OFF + m * A2_STR + n] = f2bs(v > 0.f ? v : 0.f);
                }
        }
    }
    __syncthreads();

    // L3: K=256, N=64. 4 n-tiles on waves 0..3.
    if (w < 4) {
        f32x4 acc3[2];
        acc3[0] = (f32x4){0.f, 0.f, 0.f, 0.f};
        acc3[1] = (f32x4){0.f, 0.f, 0.f, 0.f};
#pragma unroll
        for (int ks = 0; ks < 8; ++ks) {
            short8 a[2];
#pragma unroll
            for (int mt = 0; mt < 2; ++mt)
                a[mt] = *(const short8*)&sA[A2_OFF + (mt * 16 + c16) * A2_STR + ks * 32 + quad * 8];
            short8 b = *(const short8*)&W3p[((w * 8 + ks) << 9) + lane * 8];
            acc3[0] = MFMA(a[0], b, acc3[0]);
            acc3[1] = MFMA(a[1], b, acc3[1]);
        }
        int n = w * 16 + c16;
        float bv = b3[n];
#pragma unroll
        for (int mt = 0; mt < 2; ++mt)
#pragma unroll
            for (int r = 0; r < 4; ++r) {
                int m = mt * 16 + quad * 4 + r;
                float v = acc3[mt][r] + bv;
                sA[A3_OFF + m * A3_STR + n] = f2bs(v > 0.f ? v : 0.f);
            }
    }
    __syncthreads();

    // L4 + softmax: 64 threads = 32 samples x 2 classes
    if (tid < 64) {
        int m   = tid >> 1;
        int cls = tid & 1;
        float s = b4[cls];
#pragma unroll 8
        for (int k = 0; k < 64; ++k)
            s += b2f(sA[A3_OFF + m * A3_STR + k]) * W4[cls * 64 + k];
        float other = __shfl_xor(s, 1);
        float p = 1.f / (1.f + __expf(other - s));
        out[(b0 + m) * 2 + cls] = p;
    }
}

// ---------------------------------------------------------------------------
extern "C" void kernel_launch(void* const* d_in, const int* in_sizes, int n_in,
                              void* d_out, int out_size, void* d_ws, size_t ws_size,
                              hipStream_t stream)
{
    (void)in_sizes; (void)n_in; (void)out_size;
    if (ws_size < (size_t)WS_NEED) return;

    const float* x1   = (const float*)d_in[0];
    const float* x2   = (const float*)d_in[1];
    const float* W_ih = (const float*)d_in[2];
    const float* W_hh = (const float*)d_in[3];
    const float* b_ih = (const float*)d_in[4];
    const float* b_hh = (const float*)d_in[5];
    const float* W1   = (const float*)d_in[6];
    const float* b1   = (const float*)d_in[7];
    const float* W2   = (const float*)d_in[8];
    const float* b2   = (const float*)d_in[9];
    const float* W3   = (const float*)d_in[10];
    const float* b3   = (const float*)d_in[11];
    const float* W4   = (const float*)d_in[12];
    const float* b4   = (const float*)d_in[13];

    char* ws = (char*)d_ws;
    short* Wihp  = (short*)(ws + O_WIH);
    short* Whhp  = (short*)(ws + O_WHH);
    short* W1p   = (short*)(ws + O_W1);
    short* W2p   = (short*)(ws + O_W2);
    short* W3p   = (short*)(ws + O_W3);
    float* biasg = (float*)(ws + O_BG);
    float* b1p   = (float*)(ws + O_B1);

    prep_kernel<<<3461, 256, 0, stream>>>(W_ih, W_hh, b_ih, b_hh, W1, b1, W2, W3,
                                          Wihp, Whhp, biasg, W1p, b1p, W2p, W3p);
    fused_kernel<<<512, 512, 0, stream>>>(x1, x2, Wihp, Whhp, biasg,
                                          W1p, b1p, W2p, b2, W3p, b3, W4, b4,
                                          (float*)d_out);
}